// Round 2
// baseline (279.595 us; speedup 1.0000x reference)
//
#include <hip/hip_runtime.h>
#include <math.h>

typedef _Float16 h2 __attribute__((ext_vector_type(2)));

#if __has_builtin(__builtin_amdgcn_fdot2)
#define FDOT2(a,b,c) __builtin_amdgcn_fdot2((a),(b),(c),false)
#else
__device__ __forceinline__ float FDOT2(h2 a, h2 b, float c){
    return c + (float)a.x*(float)b.x + (float)a.y*(float)b.y;
}
#endif

__device__ __forceinline__ h2 pk2(float x, float y){
#if __has_builtin(__builtin_amdgcn_cvt_pkrtz)
    return __builtin_bit_cast(h2, __builtin_amdgcn_cvt_pkrtz(x, y));
#else
    h2 r; r.x = (_Float16)x; r.y = (_Float16)y; return r;
#endif
}
__device__ __forceinline__ unsigned h2u(h2 v){ return __builtin_bit_cast(unsigned, v); }
__device__ __forceinline__ h2 uh2(unsigned v){ return __builtin_bit_cast(h2, v); }

__device__ __forceinline__ float fast_rcp(float x){
#if __has_builtin(__builtin_amdgcn_rcpf)
    return __builtin_amdgcn_rcpf(x);
#else
    return 1.f/x;
#endif
}

__device__ __forceinline__ float dot8(uint4 w, uint4 v, float acc){
    acc = FDOT2(uh2(w.x), uh2(v.x), acc);
    acc = FDOT2(uh2(w.y), uh2(v.y), acc);
    acc = FDOT2(uh2(w.z), uh2(v.z), acc);
    acc = FDOT2(uh2(w.w), uh2(v.w), acc);
    return acc;
}

__device__ __forceinline__ float gelu_exact(float x){
    return 0.5f * x * (1.0f + erff(x * 0.70710678118654752f));
}

// Fused LayerNorm statistics: one interleaved butterfly computes sum(x) and
// sum(x^2) simultaneously. var = E[x^2]-mean^2, clamped >= 0.
__device__ __forceinline__ void ln_stats(float x, float& mean, float& inv){
    float s1 = x, s2 = x*x;
    #pragma unroll
    for(int off = 32; off >= 1; off >>= 1){
        s1 += __shfl_xor(s1, off, 64);
        s2 += __shfl_xor(s2, off, 64);
    }
    mean = s1 * (1.f/64.f);
    float var = fmaxf(s2 * (1.f/64.f) - mean*mean, 0.f);
    inv = rsqrtf(var + 1e-5f);
}

// same-wave LDS RAW fence: DS ops are in-order per wave; this drains lgkm and
// stops the compiler reordering LDS accesses across it. No __syncthreads needed.
__device__ __forceinline__ void lds_fence(){ __asm__ volatile("s_waitcnt lgkmcnt(0)" ::: "memory"); }

// ---------------- packed-weight layout in LDS (dword offsets) ----------------
#define W1T_OFF 0        // [64][44]  fte_w1^T pairs (81 c's, zero-padded)
#define W2T_OFF 2816     // [64][36]  fte_w2 (src [o][c])
#define WQ_OFF  5120     // [64][36]
#define FW1_OFF 7424     // [64][36]
#define FW2_OFF 9728     // [64][36]
#define WV_OFF  12032    // [64][68]
#define WP_OFF  16384    // [64][68]
#define WK_OFF  20736    // [128 c][36]: dword hp = h*4+dp holds pair (wk[c][2hp], wk[c][2hp+1])
#define WTOT    25344    // dwords = 101.4 KB

// per-pixel LDS scratch (dword offsets within a wave's region)
#define CMO   0          // cm_h  [8 j][68]: pairs over c
#define TUO   544        // tu_h / u_h [8 h][68]: pairs over c
#define CORRO 1088       // corr pairs [44]
#define QPO   1132       // generic 64-vec pair buffer [36] (q1 / qn+enc / qlin / xn / h1)
#define CCO   1168       // concat pairs [64]
#define PIXDW 1232
#define LDSDW (WTOT + 8*PIXDW)   // 35200 dw = 140,800 B

__device__ __forceinline__ float bilin(const float* __restrict__ cmap, float cx, float cy, int e){
    int i = e / 9, j = e - 9*i;
    float sx = cx + (float)(i - 4);
    float sy = cy + (float)(j - 4);
    float x0 = floorf(sx), y0 = floorf(sy);
    float wx = sx - x0,   wy = sy - y0;
    float acc = 0.f;
    #pragma unroll
    for(int dy = 0; dy < 2; dy++){
        #pragma unroll
        for(int dx = 0; dx < 2; dx++){
            float xf = x0 + (float)dx, yf = y0 + (float)dy;
            bool valid = (xf >= 0.f) && (xf <= 63.f) && (yf >= 0.f) && (yf <= 63.f);
            int xi = min(max((int)xf, 0), 63);
            int yi = min(max((int)yf, 0), 63);
            float v = valid ? cmap[yi*64 + xi] : 0.f;
            acc += v * ((dx ? wx : 1.f - wx) * (dy ? wy : 1.f - wy));
        }
    }
    return acc;
}

// Single fused kernel: grid=256 blocks x 512 threads.
// Prologue: pack raw f32 weights -> LDS f16-pair layout (per block; raw arrays
//   are ~168 KB so every block after the first hits L2/L3).
// Main: 8 waves x 4 sequential pixels (decoder transformer).
// Epilogue: each wave handles half a convex-upsample unit, registers only.
__global__ __launch_bounds__(512, 1) void decoder_fused(
    const float* __restrict__ cost_maps, const float* __restrict__ cost_memory,
    const float* __restrict__ coords1, const float* __restrict__ up_mask,
    const float* __restrict__ w1, const float* __restrict__ w2,
    const float* __restrict__ wq, const float* __restrict__ fw1,
    const float* __restrict__ fw2, const float* __restrict__ wvm,
    const float* __restrict__ wpm, const float* __restrict__ wkm,
    const float* __restrict__ fte_b1, const float* __restrict__ fte_b2,
    const float* __restrict__ ln1_g, const float* __restrict__ ln1_b,
    const float* __restrict__ ln2_g, const float* __restrict__ ln2_b,
    const float* __restrict__ bq, const float* __restrict__ bv,
    const float* __restrict__ bp, const float* __restrict__ fb1,
    const float* __restrict__ fb2, float* __restrict__ out)
{
    __shared__ unsigned sm[LDSDW];

    const int tid = threadIdx.x;
    const int wv  = tid >> 6;
    const int ln  = tid & 63;

    // ---- prologue: pack weights directly global(f32) -> LDS(f16 pairs)
    for(int idx = tid; idx < WTOT; idx += 512){
        float a = 0.f, b = 0.f;
        if(idx < W2T_OFF){                       // W1T [64][44], src w1 [o=64][c=81]
            int t = idx / 44, cp = idx % 44;
            if(2*cp   < 81) a = w1[t*81 + 2*cp];
            if(2*cp+1 < 81) b = w1[t*81 + 2*cp+1];
        } else if(idx < WQ_OFF){                 // W2T [64][36], src w2 [o=64][c=64]
            int r = idx - W2T_OFF; int t = r / 36, cp = r % 36;
            if(cp < 32){ a = w2[t*64 + 2*cp]; b = w2[t*64 + 2*cp+1]; }
        } else if(idx < FW1_OFF){                // WQ [64][36], src wq [c=64][o=64]
            int r = idx - WQ_OFF; int t = r / 36, cp = r % 36;
            if(cp < 32){ a = wq[(2*cp)*64 + t]; b = wq[(2*cp+1)*64 + t]; }
        } else if(idx < FW2_OFF){                // FW1
            int r = idx - FW1_OFF; int t = r / 36, cp = r % 36;
            if(cp < 32){ a = fw1[(2*cp)*64 + t]; b = fw1[(2*cp+1)*64 + t]; }
        } else if(idx < WV_OFF){                 // FW2
            int r = idx - FW2_OFF; int t = r / 36, cp = r % 36;
            if(cp < 32){ a = fw2[(2*cp)*64 + t]; b = fw2[(2*cp+1)*64 + t]; }
        } else if(idx < WP_OFF){                 // WV [64][68], src wv [c=128][o=64]
            int r = idx - WV_OFF; int t = r / 68, cp = r % 68;
            if(cp < 64){ a = wvm[(2*cp)*64 + t]; b = wvm[(2*cp+1)*64 + t]; }
        } else if(idx < WK_OFF){                 // WP [64][68], src wp [c=128][o=64]
            int r = idx - WP_OFF; int t = r / 68, cp = r % 68;
            if(cp < 64){ a = wpm[(2*cp)*64 + t]; b = wpm[(2*cp+1)*64 + t]; }
        } else {                                 // WK [128][36], src wk [c=128][o=64]
            int r = idx - WK_OFF; int c = r / 36, hp = r % 36;
            if(hp < 32){ a = wkm[c*64 + 2*hp]; b = wkm[c*64 + 2*hp+1]; }
        }
        sm[idx] = h2u(pk2(a, b));
    }
    // per-lane biases/ln params (lane = feature dim)
    const float b1v = fte_b1[ln], b2v = fte_b2[ln];
    const float g1v = ln1_g[ln], be1 = ln1_b[ln];
    const float g2v = ln2_g[ln], be2 = ln2_b[ln];
    const float bqv = bq[ln], bvv = bv[ln], bpv = bp[ln];
    const float f1v = fb1[ln], f2v = fb2[ln];
    __syncthreads();   // the ONLY block-wide barrier

    float* out_cg = out + 2*2*512*512;
    unsigned* P = sm + WTOT + wv * PIXDW;

    const int h_ = ln & 7;     // head (producer role)
    const int c0 = ln >> 3;    // c sub-lane (producer role)
    const int j_ = ln >> 3;    // token (K-consumer role)
    const int h3 = ln >> 3;    // head of this output dim

    int pix = blockIdx.x * 32 + wv;
    // prefetch group 0
    const float4* cm4p = (const float4*)cost_memory;
    float4 cmv0 = cm4p[(size_t)pix*256 +   0 + ln];
    float4 cmv1 = cm4p[(size_t)pix*256 +  64 + ln];
    float4 cmv2 = cm4p[(size_t)pix*256 + 128 + ln];
    float4 cmv3 = cm4p[(size_t)pix*256 + 192 + ln];
    float cx = coords1[(pix >> 12)*8192 + (pix & 4095)];
    float cy = coords1[(pix >> 12)*8192 + 4096 + (pix & 4095)];

    #pragma unroll 1
    for(int g = 0; g < 4; g++){
        // ---- stage cm pairs into LDS: value l0 = 4*(i4*64+ln), ds_write_b64
        {
            float4 v; int l0, jt, cp0;
            #define STAGE(V, I4) \
                v = V; l0 = 4*((I4)*64 + ln); jt = l0 >> 7; cp0 = (l0 & 127) >> 1; \
                { uint2 pw; pw.x = h2u(pk2(v.x, v.y)); pw.y = h2u(pk2(v.z, v.w)); \
                  *(uint2*)&P[CMO + jt*68 + cp0] = pw; }
            STAGE(cmv0, 0) STAGE(cmv1, 1) STAGE(cmv2, 2) STAGE(cmv3, 3)
            #undef STAGE
        }
        // ---- bilinear correlation window -> corr pairs (both batches issued
        // together: one HBM latency instead of two serial ones)
        {
            const float* cmap = cost_maps + (size_t)pix * 4096;
            float cv = bilin(cmap, cx, cy, ln);
            float c2 = bilin(cmap, cx, cy, 64 + ln);
            float pr = __shfl_xor(cv, 1, 64);
            if((ln & 1) == 0) P[CORRO + (ln >> 1)] = h2u(pk2(cv, pr));
            float pr2 = __shfl_xor(c2, 1, 64);
            if(ln < 17 && (ln & 1) == 0){
                float bb = (ln == 16) ? 0.f : pr2;
                P[CORRO + 32 + (ln >> 1)] = h2u(pk2(c2, bb));
            }
            if(ln < 3) P[CORRO + 41 + ln] = 0u;   // zero pads cp 41..43
        }
        // ---- prefetch next group
        int npix = pix + 8;
        float4 n0, n1, n2, n3; float ncx = 0.f, ncy = 0.f;
        if(g < 3){
            n0 = cm4p[(size_t)npix*256 +   0 + ln];
            n1 = cm4p[(size_t)npix*256 +  64 + ln];
            n2 = cm4p[(size_t)npix*256 + 128 + ln];
            n3 = cm4p[(size_t)npix*256 + 192 + ln];
            ncx = coords1[(npix >> 12)*8192 + (npix & 4095)];
            ncy = coords1[(npix >> 12)*8192 + 4096 + (npix & 4095)];
        }
        lds_fence();

        // ---- FTE1: 81->64 + GELU (dual accumulator)
        float q1;
        {
            const uint4* wr = (const uint4*)&sm[W1T_OFF + ln*44];
            const uint4* ar = (const uint4*)&P[CORRO];
            float a0 = b1v, a1 = 0.f;
            #pragma unroll
            for(int gg = 0; gg < 10; gg += 2){
                a0 = dot8(wr[gg],   ar[gg],   a0);
                a1 = dot8(wr[gg+1], ar[gg+1], a1);
            }
            a0 = dot8(wr[10], ar[10], a0);
            q1 = a0 + a1;
        }
        q1 = gelu_exact(q1);
        {   // pack q1 -> QP
            float pr = __shfl_xor(q1, 1, 64);
            if((ln & 1) == 0) P[QPO + (ln >> 1)] = h2u(pk2(q1, pr));
        }
        lds_fence();
        // ---- FTE2: 64->64 (dual accumulator)
        float shortv;
        {
            const uint4* wr = (const uint4*)&sm[W2T_OFF + ln*36];
            const uint4* ar = (const uint4*)&P[QPO];
            float a0 = b2v, a1 = 0.f;
            #pragma unroll
            for(int gg = 0; gg < 8; gg += 2){
                a0 = dot8(wr[gg],   ar[gg],   a0);
                a1 = dot8(wr[gg+1], ar[gg+1], a1);
            }
            shortv = a0 + a1;
        }
        // pack shortv half of the wp-concat NOW (covered by the qn-pack fence)
        {
            float psv = __shfl_xor(shortv, 1, 64);
            if((ln & 1) == 0) P[CCO + 32 + (ln >> 1)] = h2u(pk2(shortv, psv));
        }
        // ---- LN1 + position encoding (fused mean/var butterfly)
        float mean, inv1;
        ln_stats(shortv, mean, inv1);
        float qn = (shortv - mean) * inv1 * g1v + be1;
        {
            int   fi    = ln & 15;
            float coord = (ln < 32) ? cx : cy;
            float ang   = 3.14f * coord * (float)fi / 200.0f;
            float enc   = (ln & 16) ? __cosf(ang) : __sinf(ang);
            float qv    = qn + enc;
            float pr = __shfl_xor(qv, 1, 64);
            if((ln & 1) == 0) P[QPO + (ln >> 1)] = h2u(pk2(qv, pr));
        }
        lds_fence();
        // ---- Wq (dual accumulator), then re-pack qlin into QPO for the K path
        float qlin;
        {
            const uint4* wr = (const uint4*)&sm[WQ_OFF + ln*36];
            const uint4* ar = (const uint4*)&P[QPO];
            float a0 = bqv, a1 = 0.f;
            #pragma unroll
            for(int gg = 0; gg < 8; gg += 2){
                a0 = dot8(wr[gg],   ar[gg],   a0);
                a1 = dot8(wr[gg+1], ar[gg+1], a1);
            }
            qlin = a0 + a1;
        }
        {
            float pr = __shfl_xor(qlin, 1, 64);
            if((ln & 1) == 0) P[QPO + (ln >> 1)] = h2u(pk2(qlin, pr));
        }
        lds_fence();
        // ---- K path: t[c,h] = sum_d qlin[h,d] wk[c,h*8+d]  (bk cancels in softmax)
        {
            uint4 qh4 = *(const uint4*)&P[QPO + h_*4];
            #pragma unroll
            for(int i = 0; i < 16; i++){
                int c = c0 + 8*i;
                uint4 wk4 = *(const uint4*)&sm[WK_OFF + c*36 + h_*4];
                float tv = dot8(wk4, qh4, 0.f);
                float prt = __shfl_xor(tv, 8, 64);
                if((c0 & 1) == 0) P[TUO + h_*68 + (c0 >> 1) + 4*i] = h2u(pk2(tv, prt));
            }
        }
        lds_fence();
        // s[j,h] = sum_cp dot2(cm[j], t[h])  (quad accumulator)
        float sacc;
        {
            const int hk = ln & 7;
            const uint4* cmr = (const uint4*)&P[CMO + j_*68];
            const uint4* tur = (const uint4*)&P[TUO + hk*68];
            float s0 = 0.f, s1 = 0.f, s2 = 0.f, s3 = 0.f;
            #pragma unroll
            for(int gg = 0; gg < 16; gg += 4){
                s0 = dot8(cmr[gg],   tur[gg],   s0);
                s1 = dot8(cmr[gg+1], tur[gg+1], s1);
                s2 = dot8(cmr[gg+2], tur[gg+2], s2);
                s3 = dot8(cmr[gg+3], tur[gg+3], s3);
            }
            sacc = (s0 + s1) + (s2 + s3);
        }
        // softmax over tokens (lanes ln = j*8+h; reduce over j); probs stay in regs
        float p;
        {
            float sc = sacc * 0.35355339059327373f;
            float mx = sc;
            mx = fmaxf(mx, __shfl_xor(mx,  8, 64));
            mx = fmaxf(mx, __shfl_xor(mx, 16, 64));
            mx = fmaxf(mx, __shfl_xor(mx, 32, 64));
            float ex = __expf(sc - mx);
            float se = ex;
            se += __shfl_xor(se,  8, 64);
            se += __shfl_xor(se, 16, 64);
            se += __shfl_xor(se, 32, 64);
            p = ex * fast_rcp(se);
        }
        // ---- V path: u[h][cp] = sum_j a[j,h] cm[j][cp]; contiguous b128 blocks
        {
            float av[8];
            #pragma unroll
            for(int j = 0; j < 8; j++) av[j] = __shfl(p, j*8 + h_, 64);
            h2 u0 = pk2(0.f,0.f), u1 = u0, u2 = u0, u3 = u0;
            h2 u4 = u0, u5 = u0, u6 = u0, u7 = u0;
            #pragma unroll
            for(int j = 0; j < 8; j++){
                h2 aj = pk2(av[j], av[j]);
                const uint4* cmr = (const uint4*)&P[CMO + j*68 + 8*c0];
                uint4 qa = cmr[0], qb = cmr[1];
                u0 += aj * uh2(qa.x); u1 += aj * uh2(qa.y);
                u2 += aj * uh2(qa.z); u3 += aj * uh2(qa.w);
                u4 += aj * uh2(qb.x); u5 += aj * uh2(qb.y);
                u6 += aj * uh2(qb.z); u7 += aj * uh2(qb.w);
            }
            uint4 wa; wa.x = h2u(u0); wa.y = h2u(u1); wa.z = h2u(u2); wa.w = h2u(u3);
            uint4 wb; wb.x = h2u(u4); wb.y = h2u(u5); wb.z = h2u(u6); wb.w = h2u(u7);
            *(uint4*)&P[TUO + h_*68 + 8*c0]     = wa;
            *(uint4*)&P[TUO + h_*68 + 8*c0 + 4] = wb;
        }
        lds_fence();
        // attno = bv + sum_c u[h3][c] wv[c][ln]  (quad accumulator)
        float attno;
        {
            const uint4* ur = (const uint4*)&P[TUO + h3*68];
            const uint4* wr = (const uint4*)&sm[WV_OFF + ln*68];
            float a0 = bvv, a1 = 0.f, a2 = 0.f, a3 = 0.f;
            #pragma unroll
            for(int gg = 0; gg < 16; gg += 4){
                a0 = dot8(ur[gg],   wr[gg],   a0);
                a1 = dot8(ur[gg+1], wr[gg+1], a1);
                a2 = dot8(ur[gg+2], wr[gg+2], a2);
                a3 = dot8(ur[gg+3], wr[gg+3], a3);
            }
            attno = (a0 + a1) + (a2 + a3);
        }
        // ---- wp on concat(attno, short) + residual
        {
            float pa = __shfl_xor(attno, 1, 64);
            if((ln & 1) == 0) P[CCO + (ln >> 1)] = h2u(pk2(attno, pa));
        }
        lds_fence();
        float x;
        {
            const uint4* wr = (const uint4*)&sm[WP_OFF + ln*68];
            const uint4* ar = (const uint4*)&P[CCO];
            float a0 = bpv, a1 = 0.f, a2 = 0.f, a3 = 0.f;
            #pragma unroll
            for(int gg = 0; gg < 16; gg += 4){
                a0 = dot8(wr[gg],   ar[gg],   a0);
                a1 = dot8(wr[gg+1], ar[gg+1], a1);
                a2 = dot8(wr[gg+2], ar[gg+2], a2);
                a3 = dot8(wr[gg+3], ar[gg+3], a3);
            }
            x = (a0 + a1) + (a2 + a3);
        }
        x += shortv;
        // ---- LN2 + FFN + residual
        float m2, inv2;
        ln_stats(x, m2, inv2);
        float xn = (x - m2) * inv2 * g2v + be2;
        {
            float pr = __shfl_xor(xn, 1, 64);
            if((ln & 1) == 0) P[QPO + (ln >> 1)] = h2u(pk2(xn, pr));
        }
        lds_fence();
        float h1v;
        {
            const uint4* wr = (const uint4*)&sm[FW1_OFF + ln*36];
            const uint4* ar = (const uint4*)&P[QPO];
            float a0 = f1v, a1 = 0.f;
            #pragma unroll
            for(int gg = 0; gg < 8; gg += 2){
                a0 = dot8(wr[gg],   ar[gg],   a0);
                a1 = dot8(wr[gg+1], ar[gg+1], a1);
            }
            h1v = a0 + a1;
        }
        h1v = gelu_exact(h1v);
        {
            float pr = __shfl_xor(h1v, 1, 64);
            if((ln & 1) == 0) P[QPO + (ln >> 1)] = h2u(pk2(h1v, pr));
        }
        lds_fence();
        float f2;
        {
            const uint4* wr = (const uint4*)&sm[FW2_OFF + ln*36];
            const uint4* ar = (const uint4*)&P[QPO];
            float a0 = f2v, a1 = 0.f;
            #pragma unroll
            for(int gg = 0; gg < 8; gg += 2){
                a0 = dot8(wr[gg],   ar[gg],   a0);
                a1 = dot8(wr[gg+1], ar[gg+1], a1);
            }
            f2 = a0 + a1;
        }
        x += f2;
        // store: cost_global [B,64,64,64]
        {
            int bb = pix >> 12, hh = (pix >> 6) & 63, ww = pix & 63;
            out_cg[(((size_t)(bb*64 + ln))*64 + hh)*64 + ww] = x;
        }
        pix = npix; cx = ncx; cy = ncy;
        cmv0 = n0; cmv1 = n1; cmv2 = n2; cmv3 = n3;
    }

    // ---- epilogue: convex upsampling, half a (b,h,r) unit per wave.
    // Registers + shuffles only — no LDS, no barrier; overlaps straggler waves.
    {
        const int U  = blockIdx.x * 4 + (wv >> 1);   // unit in [0,1024)
        const int sh = (wv & 1) * 4;                 // s half: 0..3 or 4..7
        const int ub = U >> 9, uh = (U >> 3) & 63, ur = U & 7;
        const int w  = ln;

        float fx[3], fy[3];
        #pragma unroll
        for(int i = 0; i < 3; i++){
            int hh = uh + i - 1;
            bool ok = (hh >= 0) && (hh < 64);
            int hc = min(max(hh, 0), 63);
            float cxv = coords1[((ub*2 + 0)*64 + hc)*64 + w];
            float cyv = coords1[((ub*2 + 1)*64 + hc)*64 + w];
            fx[i] = ok ? 8.f * (cxv - (float)w)  : 0.f;
            fy[i] = ok ? 8.f * (cyv - (float)hh) : 0.f;
        }
        float fxm[3], fxp[3], fym[3], fyp[3];
        #pragma unroll
        for(int i = 0; i < 3; i++){
            fxm[i] = __shfl(fx[i], w - 1, 64);
            fxp[i] = __shfl(fx[i], w + 1, 64);
            fym[i] = __shfl(fy[i], w - 1, 64);
            fyp[i] = __shfl(fy[i], w + 1, 64);
            if(w == 0) { fxm[i] = 0.f; fym[i] = 0.f; }
            if(w == 63){ fxp[i] = 0.f; fyp[i] = 0.f; }
        }
        float m[36];
        #pragma unroll
        for(int k = 0; k < 9; k++){
            #pragma unroll
            for(int si = 0; si < 4; si++){
                int c = k*64 + ur*8 + sh + si;
                m[k*4 + si] = up_mask[(((size_t)ub*576 + c)*64 + uh)*64 + w];
            }
        }
        float outx[4], outy[4];
        #pragma unroll
        for(int si = 0; si < 4; si++){
            float mx = m[si];
            #pragma unroll
            for(int k = 1; k < 9; k++) mx = fmaxf(mx, m[k*4 + si]);
            float e, se = 0.f, ox = 0.f, oy = 0.f;
            #pragma unroll
            for(int k = 0; k < 9; k++){
                e = __expf(m[k*4 + si] - mx);
                se += e;
                int i = k / 3, j = k % 3;
                float fxv = (j == 0) ? fxm[i] : ((j == 1) ? fx[i] : fxp[i]);
                float fyv = (j == 0) ? fym[i] : ((j == 1) ? fy[i] : fyp[i]);
                ox += e * fxv;
                oy += e * fyv;
            }
            float inv = fast_rcp(se);
            outx[si] = ox * inv;
            outy[si] = oy * inv;
        }
        size_t row = (size_t)(uh*8 + ur) * 512 + w*8 + sh;
        *(float4*)&out[(size_t)(ub*2 + 0)*262144 + row] = *(const float4*)outx;
        *(float4*)&out[(size_t)(ub*2 + 1)*262144 + row] = *(const float4*)outy;
    }
}

extern "C" void kernel_launch(void* const* d_in, const int* in_sizes, int n_in,
                              void* d_out, int out_size, void* d_ws, size_t ws_size,
                              hipStream_t stream)
{
    const float* cost_maps   = (const float*)d_in[0];
    const float* cost_memory = (const float*)d_in[1];
    const float* coords1     = (const float*)d_in[2];
    const float* up_mask     = (const float*)d_in[3];
    const float* fte_w1      = (const float*)d_in[4];
    const float* fte_b1      = (const float*)d_in[5];
    const float* fte_w2      = (const float*)d_in[6];
    const float* fte_b2      = (const float*)d_in[7];
    const float* ln1_g       = (const float*)d_in[8];
    const float* ln1_b       = (const float*)d_in[9];
    const float* ln2_g       = (const float*)d_in[10];
    const float* ln2_b       = (const float*)d_in[11];
    const float* wq          = (const float*)d_in[12];
    const float* bq          = (const float*)d_in[13];
    const float* wk          = (const float*)d_in[14];
    const float* bv          = (const float*)d_in[17];
    const float* wv          = (const float*)d_in[16];
    const float* wp          = (const float*)d_in[18];
    const float* bp          = (const float*)d_in[19];
    const float* fw1         = (const float*)d_in[20];
    const float* fb1         = (const float*)d_in[21];
    const float* fw2         = (const float*)d_in[22];
    const float* fb2         = (const float*)d_in[23];
    float* out = (float*)d_out;
    (void)d_ws; (void)ws_size;

    decoder_fused<<<256, 512, 0, stream>>>(
        cost_maps, cost_memory, coords1, up_mask,
        fte_w1, fte_w2, wq, fw1, fw2, wv, wp, wk,
        fte_b1, fte_b2, ln1_g, ln1_b, ln2_g, ln2_b,
        bq, bv, bp, fb1, fb2,
        out);
}

// Round 3
// 265.568 us; speedup vs baseline: 1.0528x; 1.0528x over previous
//
#include <hip/hip_runtime.h>
#include <math.h>

typedef _Float16 h2 __attribute__((ext_vector_type(2)));

#if __has_builtin(__builtin_amdgcn_fdot2)
#define FDOT2(a,b,c) __builtin_amdgcn_fdot2((a),(b),(c),false)
#else
__device__ __forceinline__ float FDOT2(h2 a, h2 b, float c){
    return c + (float)a.x*(float)b.x + (float)a.y*(float)b.y;
}
#endif

__device__ __forceinline__ h2 pk2(float x, float y){
#if __has_builtin(__builtin_amdgcn_cvt_pkrtz)
    return __builtin_bit_cast(h2, __builtin_amdgcn_cvt_pkrtz(x, y));
#else
    h2 r; r.x = (_Float16)x; r.y = (_Float16)y; return r;
#endif
}
__device__ __forceinline__ unsigned h2u(h2 v){ return __builtin_bit_cast(unsigned, v); }
__device__ __forceinline__ h2 uh2(unsigned v){ return __builtin_bit_cast(h2, v); }

__device__ __forceinline__ float fast_rcp(float x){
#if __has_builtin(__builtin_amdgcn_rcpf)
    return __builtin_amdgcn_rcpf(x);
#else
    return 1.f/x;
#endif
}

__device__ __forceinline__ float dot8(uint4 w, uint4 v, float acc){
    acc = FDOT2(uh2(w.x), uh2(v.x), acc);
    acc = FDOT2(uh2(w.y), uh2(v.y), acc);
    acc = FDOT2(uh2(w.z), uh2(v.z), acc);
    acc = FDOT2(uh2(w.w), uh2(v.w), acc);
    return acc;
}

__device__ __forceinline__ float gelu_exact(float x){
    return 0.5f * x * (1.0f + erff(x * 0.70710678118654752f));
}

// Fused LayerNorm statistics: one interleaved butterfly computes sum(x) and
// sum(x^2) simultaneously. var = E[x^2]-mean^2, clamped >= 0.
__device__ __forceinline__ void ln_stats(float x, float& mean, float& inv){
    float s1 = x, s2 = x*x;
    #pragma unroll
    for(int off = 32; off >= 1; off >>= 1){
        s1 += __shfl_xor(s1, off, 64);
        s2 += __shfl_xor(s2, off, 64);
    }
    mean = s1 * (1.f/64.f);
    float var = fmaxf(s2 * (1.f/64.f) - mean*mean, 0.f);
    inv = rsqrtf(var + 1e-5f);
}

// same-wave LDS RAW fence: DS ops are in-order per wave; this drains lgkm and
// stops the compiler reordering LDS accesses across it. No __syncthreads needed.
__device__ __forceinline__ void lds_fence(){ __asm__ volatile("s_waitcnt lgkmcnt(0)" ::: "memory"); }

// ---------------- packed-weight layout in d_ws (dword offsets) ----------------
// Packed ONCE by prep_weights (the gather-transpose patterns are uncoalesced;
// doing them per-block in the main kernel cost +14 µs in round 2). The main
// kernel copies d_ws -> LDS with fully-coalesced uint4 loads instead.
#define W1T_OFF 0        // [64][44]  fte_w1^T pairs (81 c's, zero-padded)
#define W2T_OFF 2816     // [64][36]  fte_w2 (src [o][c])
#define WQ_OFF  5120     // [64][36]
#define FW1_OFF 7424     // [64][36]
#define FW2_OFF 9728     // [64][36]
#define WV_OFF  12032    // [64][68]
#define WP_OFF  16384    // [64][68]
#define WK_OFF  20736    // [128 c][36]: dword hp = h*4+dp holds pair (wk[c][2hp], wk[c][2hp+1])
#define WTOT    25344    // dwords = 101.4 KB

// per-pixel LDS scratch (dword offsets within a wave's region)
#define CMO   0          // cm_h  [8 j][68]: pairs over c
#define TUO   544        // tu_h / u_h [8 h][68]: pairs over c
#define CORRO 1088       // corr pairs [44]
#define QPO   1132       // generic 64-vec pair buffer [36] (q1 / qn+enc / qlin / xn / h1)
#define CCO   1168       // concat pairs [64]
#define PIXDW 1232
#define LDSDW (WTOT + 8*PIXDW)   // 35200 dw = 140,800 B

// K0: pack all weight matrices to f16-pair layouts in d_ws (runs once, ~2 µs).
__global__ void prep_weights(const float* __restrict__ w1, const float* __restrict__ w2,
                             const float* __restrict__ wq, const float* __restrict__ fw1,
                             const float* __restrict__ fw2, const float* __restrict__ wv,
                             const float* __restrict__ wp, const float* __restrict__ wk,
                             unsigned* __restrict__ ws){
    int idx = blockIdx.x * blockDim.x + threadIdx.x;
    if(idx >= WTOT) return;
    float a = 0.f, b = 0.f;
    if(idx < W2T_OFF){                       // W1T [64][44], src w1 [o=64][c=81]
        int t = idx / 44, cp = idx % 44;
        if(2*cp   < 81) a = w1[t*81 + 2*cp];
        if(2*cp+1 < 81) b = w1[t*81 + 2*cp+1];
    } else if(idx < WQ_OFF){                 // W2T [64][36], src w2 [o=64][c=64]
        int r = idx - W2T_OFF; int t = r / 36, cp = r % 36;
        if(cp < 32){ a = w2[t*64 + 2*cp]; b = w2[t*64 + 2*cp+1]; }
    } else if(idx < FW1_OFF){                // WQ [64][36], src wq [c=64][o=64]
        int r = idx - WQ_OFF; int t = r / 36, cp = r % 36;
        if(cp < 32){ a = wq[(2*cp)*64 + t]; b = wq[(2*cp+1)*64 + t]; }
    } else if(idx < FW2_OFF){                // FW1
        int r = idx - FW1_OFF; int t = r / 36, cp = r % 36;
        if(cp < 32){ a = fw1[(2*cp)*64 + t]; b = fw1[(2*cp+1)*64 + t]; }
    } else if(idx < WV_OFF){                 // FW2
        int r = idx - FW2_OFF; int t = r / 36, cp = r % 36;
        if(cp < 32){ a = fw2[(2*cp)*64 + t]; b = fw2[(2*cp+1)*64 + t]; }
    } else if(idx < WP_OFF){                 // WV [64][68], src wv [c=128][o=64]
        int r = idx - WV_OFF; int t = r / 68, cp = r % 68;
        if(cp < 64){ a = wv[(2*cp)*64 + t]; b = wv[(2*cp+1)*64 + t]; }
    } else if(idx < WK_OFF){                 // WP [64][68], src wp [c=128][o=64]
        int r = idx - WK_OFF; int t = r / 68, cp = r % 68;
        if(cp < 64){ a = wp[(2*cp)*64 + t]; b = wp[(2*cp+1)*64 + t]; }
    } else {                                 // WK [128][36], src wk [c=128][o=64]
        int r = idx - WK_OFF; int c = r / 36, hp = r % 36;
        if(hp < 32){ a = wk[c*64 + 2*hp]; b = wk[c*64 + 2*hp+1]; }
    }
    ws[idx] = h2u(pk2(a, b));
}

__device__ __forceinline__ float bilin(const float* __restrict__ cmap, float cx, float cy, int e){
    int i = e / 9, j = e - 9*i;
    float sx = cx + (float)(i - 4);
    float sy = cy + (float)(j - 4);
    float x0 = floorf(sx), y0 = floorf(sy);
    float wx = sx - x0,   wy = sy - y0;
    float acc = 0.f;
    #pragma unroll
    for(int dy = 0; dy < 2; dy++){
        #pragma unroll
        for(int dx = 0; dx < 2; dx++){
            float xf = x0 + (float)dx, yf = y0 + (float)dy;
            bool valid = (xf >= 0.f) && (xf <= 63.f) && (yf >= 0.f) && (yf <= 63.f);
            int xi = min(max((int)xf, 0), 63);
            int yi = min(max((int)yf, 0), 63);
            float v = valid ? cmap[yi*64 + xi] : 0.f;
            acc += v * ((dx ? wx : 1.f - wx) * (dy ? wy : 1.f - wy));
        }
    }
    return acc;
}

// Main kernel: grid=256 blocks x 512 threads. Weights live in LDS (coalesced
// copy from packed d_ws); 8 waves x 4 sequential pixels; then each wave runs
// half a convex-upsample unit as a registers-only epilogue (no extra launch).
__global__ __launch_bounds__(512, 1) void decoder_main(
    const float* __restrict__ cost_maps, const float* __restrict__ cost_memory,
    const float* __restrict__ coords1, const float* __restrict__ up_mask,
    const unsigned* __restrict__ ws,
    const float* __restrict__ fte_b1, const float* __restrict__ fte_b2,
    const float* __restrict__ ln1_g, const float* __restrict__ ln1_b,
    const float* __restrict__ ln2_g, const float* __restrict__ ln2_b,
    const float* __restrict__ bq, const float* __restrict__ bv,
    const float* __restrict__ bp, const float* __restrict__ fb1,
    const float* __restrict__ fb2, float* __restrict__ out)
{
    __shared__ unsigned sm[LDSDW];

    const int tid = threadIdx.x;
    const int wv  = tid >> 6;
    const int ln  = tid & 63;

    int pix = blockIdx.x * 32 + wv;
    // ---- group-0 prefetch FIRST: HBM latency hides under the weight copy
    const float4* cm4p = (const float4*)cost_memory;
    float4 cmv0 = cm4p[(size_t)pix*256 +   0 + ln];
    float4 cmv1 = cm4p[(size_t)pix*256 +  64 + ln];
    float4 cmv2 = cm4p[(size_t)pix*256 + 128 + ln];
    float4 cmv3 = cm4p[(size_t)pix*256 + 192 + ln];
    float cx = coords1[(pix >> 12)*8192 + (pix & 4095)];
    float cy = coords1[(pix >> 12)*8192 + 4096 + (pix & 4095)];

    // ---- cooperative weight copy d_ws -> LDS (uint4, coalesced)
    {
        const uint4* src = (const uint4*)ws;
        uint4* dst = (uint4*)sm;
        for(int i = tid; i < WTOT/4; i += 512) dst[i] = src[i];
    }
    // per-lane biases/ln params (lane = feature dim)
    const float b1v = fte_b1[ln], b2v = fte_b2[ln];
    const float g1v = ln1_g[ln], be1 = ln1_b[ln];
    const float g2v = ln2_g[ln], be2 = ln2_b[ln];
    const float bqv = bq[ln], bvv = bv[ln], bpv = bp[ln];
    const float f1v = fb1[ln], f2v = fb2[ln];
    __syncthreads();   // the ONLY block-wide barrier

    float* out_cg = out + 2*2*512*512;
    unsigned* P = sm + WTOT + wv * PIXDW;

    const int h_ = ln & 7;     // head (producer role)
    const int c0 = ln >> 3;    // c sub-lane (producer role)
    const int j_ = ln >> 3;    // token (K-consumer role)
    const int h3 = ln >> 3;    // head of this output dim

    #pragma unroll 1
    for(int g = 0; g < 4; g++){
        // ---- stage cm pairs into LDS: value l0 = 4*(i4*64+ln), ds_write_b64
        {
            float4 v; int l0, jt, cp0;
            #define STAGE(V, I4) \
                v = V; l0 = 4*((I4)*64 + ln); jt = l0 >> 7; cp0 = (l0 & 127) >> 1; \
                { uint2 pw; pw.x = h2u(pk2(v.x, v.y)); pw.y = h2u(pk2(v.z, v.w)); \
                  *(uint2*)&P[CMO + jt*68 + cp0] = pw; }
            STAGE(cmv0, 0) STAGE(cmv1, 1) STAGE(cmv2, 2) STAGE(cmv3, 3)
            #undef STAGE
        }
        // ---- bilinear correlation window -> corr pairs (both batches issued
        // together: one HBM latency instead of two serial ones)
        {
            const float* cmap = cost_maps + (size_t)pix * 4096;
            float cv = bilin(cmap, cx, cy, ln);
            float c2 = bilin(cmap, cx, cy, 64 + ln);
            float pr = __shfl_xor(cv, 1, 64);
            if((ln & 1) == 0) P[CORRO + (ln >> 1)] = h2u(pk2(cv, pr));
            float pr2 = __shfl_xor(c2, 1, 64);
            if(ln < 17 && (ln & 1) == 0){
                float bb = (ln == 16) ? 0.f : pr2;
                P[CORRO + 32 + (ln >> 1)] = h2u(pk2(c2, bb));
            }
            if(ln < 3) P[CORRO + 41 + ln] = 0u;   // zero pads cp 41..43
        }
        // ---- prefetch next group
        int npix = pix + 8;
        float4 n0, n1, n2, n3; float ncx = 0.f, ncy = 0.f;
        if(g < 3){
            n0 = cm4p[(size_t)npix*256 +   0 + ln];
            n1 = cm4p[(size_t)npix*256 +  64 + ln];
            n2 = cm4p[(size_t)npix*256 + 128 + ln];
            n3 = cm4p[(size_t)npix*256 + 192 + ln];
            ncx = coords1[(npix >> 12)*8192 + (npix & 4095)];
            ncy = coords1[(npix >> 12)*8192 + 4096 + (npix & 4095)];
        }
        lds_fence();

        // ---- FTE1: 81->64 + GELU (dual accumulator)
        float q1;
        {
            const uint4* wr = (const uint4*)&sm[W1T_OFF + ln*44];
            const uint4* ar = (const uint4*)&P[CORRO];
            float a0 = b1v, a1 = 0.f;
            #pragma unroll
            for(int gg = 0; gg < 10; gg += 2){
                a0 = dot8(wr[gg],   ar[gg],   a0);
                a1 = dot8(wr[gg+1], ar[gg+1], a1);
            }
            a0 = dot8(wr[10], ar[10], a0);
            q1 = a0 + a1;
        }
        q1 = gelu_exact(q1);
        {   // pack q1 -> QP
            float pr = __shfl_xor(q1, 1, 64);
            if((ln & 1) == 0) P[QPO + (ln >> 1)] = h2u(pk2(q1, pr));
        }
        lds_fence();
        // ---- FTE2: 64->64 (dual accumulator)
        float shortv;
        {
            const uint4* wr = (const uint4*)&sm[W2T_OFF + ln*36];
            const uint4* ar = (const uint4*)&P[QPO];
            float a0 = b2v, a1 = 0.f;
            #pragma unroll
            for(int gg = 0; gg < 8; gg += 2){
                a0 = dot8(wr[gg],   ar[gg],   a0);
                a1 = dot8(wr[gg+1], ar[gg+1], a1);
            }
            shortv = a0 + a1;
        }
        // pack shortv half of the wp-concat NOW (covered by the qn-pack fence)
        {
            float psv = __shfl_xor(shortv, 1, 64);
            if((ln & 1) == 0) P[CCO + 32 + (ln >> 1)] = h2u(pk2(shortv, psv));
        }
        // ---- LN1 + position encoding (fused mean/var butterfly)
        float mean, inv1;
        ln_stats(shortv, mean, inv1);
        float qn = (shortv - mean) * inv1 * g1v + be1;
        {
            int   fi    = ln & 15;
            float coord = (ln < 32) ? cx : cy;
            float ang   = 3.14f * coord * (float)fi / 200.0f;
            float enc   = (ln & 16) ? __cosf(ang) : __sinf(ang);
            float qv    = qn + enc;
            float pr = __shfl_xor(qv, 1, 64);
            if((ln & 1) == 0) P[QPO + (ln >> 1)] = h2u(pk2(qv, pr));
        }
        lds_fence();
        // ---- Wq (dual accumulator), then re-pack qlin into QPO for the K path
        float qlin;
        {
            const uint4* wr = (const uint4*)&sm[WQ_OFF + ln*36];
            const uint4* ar = (const uint4*)&P[QPO];
            float a0 = bqv, a1 = 0.f;
            #pragma unroll
            for(int gg = 0; gg < 8; gg += 2){
                a0 = dot8(wr[gg],   ar[gg],   a0);
                a1 = dot8(wr[gg+1], ar[gg+1], a1);
            }
            qlin = a0 + a1;
        }
        {
            float pr = __shfl_xor(qlin, 1, 64);
            if((ln & 1) == 0) P[QPO + (ln >> 1)] = h2u(pk2(qlin, pr));
        }
        lds_fence();
        // ---- K path: t[c,h] = sum_d qlin[h,d] wk[c,h*8+d]  (bk cancels in softmax)
        {
            uint4 qh4 = *(const uint4*)&P[QPO + h_*4];
            #pragma unroll
            for(int i = 0; i < 16; i++){
                int c = c0 + 8*i;
                uint4 wk4 = *(const uint4*)&sm[WK_OFF + c*36 + h_*4];
                float tv = dot8(wk4, qh4, 0.f);
                float prt = __shfl_xor(tv, 8, 64);
                if((c0 & 1) == 0) P[TUO + h_*68 + (c0 >> 1) + 4*i] = h2u(pk2(tv, prt));
            }
        }
        lds_fence();
        // s[j,h] = sum_cp dot2(cm[j], t[h])  (quad accumulator)
        float sacc;
        {
            const int hk = ln & 7;
            const uint4* cmr = (const uint4*)&P[CMO + j_*68];
            const uint4* tur = (const uint4*)&P[TUO + hk*68];
            float s0 = 0.f, s1 = 0.f, s2 = 0.f, s3 = 0.f;
            #pragma unroll
            for(int gg = 0; gg < 16; gg += 4){
                s0 = dot8(cmr[gg],   tur[gg],   s0);
                s1 = dot8(cmr[gg+1], tur[gg+1], s1);
                s2 = dot8(cmr[gg+2], tur[gg+2], s2);
                s3 = dot8(cmr[gg+3], tur[gg+3], s3);
            }
            sacc = (s0 + s1) + (s2 + s3);
        }
        // softmax over tokens (lanes ln = j*8+h; reduce over j); probs stay in regs
        float p;
        {
            float sc = sacc * 0.35355339059327373f;
            float mx = sc;
            mx = fmaxf(mx, __shfl_xor(mx,  8, 64));
            mx = fmaxf(mx, __shfl_xor(mx, 16, 64));
            mx = fmaxf(mx, __shfl_xor(mx, 32, 64));
            float ex = __expf(sc - mx);
            float se = ex;
            se += __shfl_xor(se,  8, 64);
            se += __shfl_xor(se, 16, 64);
            se += __shfl_xor(se, 32, 64);
            p = ex * fast_rcp(se);
        }
        // ---- V path: u[h][cp] = sum_j a[j,h] cm[j][cp]; contiguous b128 blocks
        {
            float av[8];
            #pragma unroll
            for(int j = 0; j < 8; j++) av[j] = __shfl(p, j*8 + h_, 64);
            h2 u0 = pk2(0.f,0.f), u1 = u0, u2 = u0, u3 = u0;
            h2 u4 = u0, u5 = u0, u6 = u0, u7 = u0;
            #pragma unroll
            for(int j = 0; j < 8; j++){
                h2 aj = pk2(av[j], av[j]);
                const uint4* cmr = (const uint4*)&P[CMO + j*68 + 8*c0];
                uint4 qa = cmr[0], qb = cmr[1];
                u0 += aj * uh2(qa.x); u1 += aj * uh2(qa.y);
                u2 += aj * uh2(qa.z); u3 += aj * uh2(qa.w);
                u4 += aj * uh2(qb.x); u5 += aj * uh2(qb.y);
                u6 += aj * uh2(qb.z); u7 += aj * uh2(qb.w);
            }
            uint4 wa; wa.x = h2u(u0); wa.y = h2u(u1); wa.z = h2u(u2); wa.w = h2u(u3);
            uint4 wb; wb.x = h2u(u4); wb.y = h2u(u5); wb.z = h2u(u6); wb.w = h2u(u7);
            *(uint4*)&P[TUO + h_*68 + 8*c0]     = wa;
            *(uint4*)&P[TUO + h_*68 + 8*c0 + 4] = wb;
        }
        lds_fence();
        // attno = bv + sum_c u[h3][c] wv[c][ln]  (quad accumulator)
        float attno;
        {
            const uint4* ur = (const uint4*)&P[TUO + h3*68];
            const uint4* wr = (const uint4*)&sm[WV_OFF + ln*68];
            float a0 = bvv, a1 = 0.f, a2 = 0.f, a3 = 0.f;
            #pragma unroll
            for(int gg = 0; gg < 16; gg += 4){
                a0 = dot8(ur[gg],   wr[gg],   a0);
                a1 = dot8(ur[gg+1], wr[gg+1], a1);
                a2 = dot8(ur[gg+2], wr[gg+2], a2);
                a3 = dot8(ur[gg+3], wr[gg+3], a3);
            }
            attno = (a0 + a1) + (a2 + a3);
        }
        // ---- wp on concat(attno, short) + residual
        {
            float pa = __shfl_xor(attno, 1, 64);
            if((ln & 1) == 0) P[CCO + (ln >> 1)] = h2u(pk2(attno, pa));
        }
        lds_fence();
        float x;
        {
            const uint4* wr = (const uint4*)&sm[WP_OFF + ln*68];
            const uint4* ar = (const uint4*)&P[CCO];
            float a0 = bpv, a1 = 0.f, a2 = 0.f, a3 = 0.f;
            #pragma unroll
            for(int gg = 0; gg < 16; gg += 4){
                a0 = dot8(wr[gg],   ar[gg],   a0);
                a1 = dot8(wr[gg+1], ar[gg+1], a1);
                a2 = dot8(wr[gg+2], ar[gg+2], a2);
                a3 = dot8(wr[gg+3], ar[gg+3], a3);
            }
            x = (a0 + a1) + (a2 + a3);
        }
        x += shortv;
        // ---- LN2 + FFN + residual
        float m2, inv2;
        ln_stats(x, m2, inv2);
        float xn = (x - m2) * inv2 * g2v + be2;
        {
            float pr = __shfl_xor(xn, 1, 64);
            if((ln & 1) == 0) P[QPO + (ln >> 1)] = h2u(pk2(xn, pr));
        }
        lds_fence();
        float h1v;
        {
            const uint4* wr = (const uint4*)&sm[FW1_OFF + ln*36];
            const uint4* ar = (const uint4*)&P[QPO];
            float a0 = f1v, a1 = 0.f;
            #pragma unroll
            for(int gg = 0; gg < 8; gg += 2){
                a0 = dot8(wr[gg],   ar[gg],   a0);
                a1 = dot8(wr[gg+1], ar[gg+1], a1);
            }
            h1v = a0 + a1;
        }
        h1v = gelu_exact(h1v);
        {
            float pr = __shfl_xor(h1v, 1, 64);
            if((ln & 1) == 0) P[QPO + (ln >> 1)] = h2u(pk2(h1v, pr));
        }
        lds_fence();
        float f2;
        {
            const uint4* wr = (const uint4*)&sm[FW2_OFF + ln*36];
            const uint4* ar = (const uint4*)&P[QPO];
            float a0 = f2v, a1 = 0.f;
            #pragma unroll
            for(int gg = 0; gg < 8; gg += 2){
                a0 = dot8(wr[gg],   ar[gg],   a0);
                a1 = dot8(wr[gg+1], ar[gg+1], a1);
            }
            f2 = a0 + a1;
        }
        x += f2;
        // store: cost_global [B,64,64,64]
        {
            int bb = pix >> 12, hh = (pix >> 6) & 63, ww = pix & 63;
            out_cg[(((size_t)(bb*64 + ln))*64 + hh)*64 + ww] = x;
        }
        pix = npix; cx = ncx; cy = ncy;
        cmv0 = n0; cmv1 = n1; cmv2 = n2; cmv3 = n3;
    }

    // ---- epilogue: convex upsampling, half a (b,h,r) unit per wave.
    // Registers + shuffles only — no LDS, no barrier; overlaps straggler waves.
    {
        const int U  = blockIdx.x * 4 + (wv >> 1);   // unit in [0,1024)
        const int sh = (wv & 1) * 4;                 // s half: 0..3 or 4..7
        const int ub = U >> 9, uh = (U >> 3) & 63, ur = U & 7;
        const int w  = ln;

        float fx[3], fy[3];
        #pragma unroll
        for(int i = 0; i < 3; i++){
            int hh = uh + i - 1;
            bool ok = (hh >= 0) && (hh < 64);
            int hc = min(max(hh, 0), 63);
            float cxv = coords1[((ub*2 + 0)*64 + hc)*64 + w];
            float cyv = coords1[((ub*2 + 1)*64 + hc)*64 + w];
            fx[i] = ok ? 8.f * (cxv - (float)w)  : 0.f;
            fy[i] = ok ? 8.f * (cyv - (float)hh) : 0.f;
        }
        float fxm[3], fxp[3], fym[3], fyp[3];
        #pragma unroll
        for(int i = 0; i < 3; i++){
            fxm[i] = __shfl(fx[i], w - 1, 64);
            fxp[i] = __shfl(fx[i], w + 1, 64);
            fym[i] = __shfl(fy[i], w - 1, 64);
            fyp[i] = __shfl(fy[i], w + 1, 64);
            if(w == 0) { fxm[i] = 0.f; fym[i] = 0.f; }
            if(w == 63){ fxp[i] = 0.f; fyp[i] = 0.f; }
        }
        float m[36];
        #pragma unroll
        for(int k = 0; k < 9; k++){
            #pragma unroll
            for(int si = 0; si < 4; si++){
                int c = k*64 + ur*8 + sh + si;
                m[k*4 + si] = up_mask[(((size_t)ub*576 + c)*64 + uh)*64 + w];
            }
        }
        float outx[4], outy[4];
        #pragma unroll
        for(int si = 0; si < 4; si++){
            float mx = m[si];
            #pragma unroll
            for(int k = 1; k < 9; k++) mx = fmaxf(mx, m[k*4 + si]);
            float e, se = 0.f, ox = 0.f, oy = 0.f;
            #pragma unroll
            for(int k = 0; k < 9; k++){
                e = __expf(m[k*4 + si] - mx);
                se += e;
                int i = k / 3, j = k % 3;
                float fxv = (j == 0) ? fxm[i] : ((j == 1) ? fx[i] : fxp[i]);
                float fyv = (j == 0) ? fym[i] : ((j == 1) ? fy[i] : fyp[i]);
                ox += e * fxv;
                oy += e * fyv;
            }
            float inv = fast_rcp(se);
            outx[si] = ox * inv;
            outy[si] = oy * inv;
        }
        size_t row = (size_t)(uh*8 + ur) * 512 + w*8 + sh;
        *(float4*)&out[(size_t)(ub*2 + 0)*262144 + row] = *(const float4*)outx;
        *(float4*)&out[(size_t)(ub*2 + 1)*262144 + row] = *(const float4*)outy;
    }
}

extern "C" void kernel_launch(void* const* d_in, const int* in_sizes, int n_in,
                              void* d_out, int out_size, void* d_ws, size_t ws_size,
                              hipStream_t stream)
{
    const float* cost_maps   = (const float*)d_in[0];
    const float* cost_memory = (const float*)d_in[1];
    const float* coords1     = (const float*)d_in[2];
    const float* up_mask     = (const float*)d_in[3];
    const float* fte_w1      = (const float*)d_in[4];
    const float* fte_b1      = (const float*)d_in[5];
    const float* fte_w2      = (const float*)d_in[6];
    const float* fte_b2      = (const float*)d_in[7];
    const float* ln1_g       = (const float*)d_in[8];
    const float* ln1_b       = (const float*)d_in[9];
    const float* ln2_g       = (const float*)d_in[10];
    const float* ln2_b       = (const float*)d_in[11];
    const float* wq          = (const float*)d_in[12];
    const float* bq          = (const float*)d_in[13];
    const float* wk          = (const float*)d_in[14];
    const float* bv          = (const float*)d_in[17];
    const float* wv          = (const float*)d_in[16];
    const float* wp          = (const float*)d_in[18];
    const float* bp          = (const float*)d_in[19];
    const float* fw1         = (const float*)d_in[20];
    const float* fb1         = (const float*)d_in[21];
    const float* fw2         = (const float*)d_in[22];
    const float* fb2         = (const float*)d_in[23];
    float* out = (float*)d_out;
    unsigned* wsu = (unsigned*)d_ws;

    prep_weights<<<(WTOT + 511)/512, 512, 0, stream>>>(
        fte_w1, fte_w2, wq, fw1, fw2, wv, wp, wk, wsu);

    decoder_main<<<256, 512, 0, stream>>>(
        cost_maps, cost_memory, coords1, up_mask, wsu,
        fte_b1, fte_b2, ln1_g, ln1_b, ln2_g, ln2_b,
        bq, bv, bp, fb1, fb2,
        out);
}

// Round 4
// 259.046 us; speedup vs baseline: 1.0793x; 1.0252x over previous
//
#include <hip/hip_runtime.h>
#include <math.h>

typedef _Float16 h2 __attribute__((ext_vector_type(2)));

#if __has_builtin(__builtin_amdgcn_fdot2)
#define FDOT2(a,b,c) __builtin_amdgcn_fdot2((a),(b),(c),false)
#else
__device__ __forceinline__ float FDOT2(h2 a, h2 b, float c){
    return c + (float)a.x*(float)b.x + (float)a.y*(float)b.y;
}
#endif

__device__ __forceinline__ h2 pk2(float x, float y){
#if __has_builtin(__builtin_amdgcn_cvt_pkrtz)
    return __builtin_bit_cast(h2, __builtin_amdgcn_cvt_pkrtz(x, y));
#else
    h2 r; r.x = (_Float16)x; r.y = (_Float16)y; return r;
#endif
}
__device__ __forceinline__ unsigned h2u(h2 v){ return __builtin_bit_cast(unsigned, v); }
__device__ __forceinline__ h2 uh2(unsigned v){ return __builtin_bit_cast(h2, v); }

__device__ __forceinline__ float fast_rcp(float x){
#if __has_builtin(__builtin_amdgcn_rcpf)
    return __builtin_amdgcn_rcpf(x);
#else
    return 1.f/x;
#endif
}

__device__ __forceinline__ float dot8(uint4 w, uint4 v, float acc){
    acc = FDOT2(uh2(w.x), uh2(v.x), acc);
    acc = FDOT2(uh2(w.y), uh2(v.y), acc);
    acc = FDOT2(uh2(w.z), uh2(v.z), acc);
    acc = FDOT2(uh2(w.w), uh2(v.w), acc);
    return acc;
}

__device__ __forceinline__ float gelu_exact(float x){
    return 0.5f * x * (1.0f + erff(x * 0.70710678118654752f));
}

// Fused LayerNorm statistics: one interleaved butterfly computes sum(x) and
// sum(x^2) simultaneously. var = E[x^2]-mean^2, clamped >= 0.
__device__ __forceinline__ void ln_stats(float x, float& mean, float& inv){
    float s1 = x, s2 = x*x;
    #pragma unroll
    for(int off = 32; off >= 1; off >>= 1){
        s1 += __shfl_xor(s1, off, 64);
        s2 += __shfl_xor(s2, off, 64);
    }
    mean = s1 * (1.f/64.f);
    float var = fmaxf(s2 * (1.f/64.f) - mean*mean, 0.f);
    inv = rsqrtf(var + 1e-5f);
}

// same-wave LDS RAW fence: DS ops are in-order per wave; this drains lgkm and
// stops the compiler reordering LDS accesses across it. No __syncthreads needed.
__device__ __forceinline__ void lds_fence(){ __asm__ volatile("s_waitcnt lgkmcnt(0)" ::: "memory"); }

// ---------------- packed-weight layout in d_ws (dword offsets) ----------------
// Packed ONCE by prep_weights (the gather-transpose patterns are uncoalesced;
// doing them per-block in the main kernel cost +14 µs in round 2). The main
// kernel copies d_ws -> LDS with fully-coalesced uint4 loads instead.
#define W1T_OFF 0        // [64][44]  fte_w1^T pairs (81 c's, zero-padded)
#define W2T_OFF 2816     // [64][36]  fte_w2 (src [o][c])
#define WQ_OFF  5120     // [64][36]
#define FW1_OFF 7424     // [64][36]
#define FW2_OFF 9728     // [64][36]
#define WV_OFF  12032    // [64][68]
#define WP_OFF  16384    // [64][68]
#define WK_OFF  20736    // [128 c][36]: dword hp = h*4+dp holds pair (wk[c][2hp], wk[c][2hp+1])
#define WTOT    25344    // dwords = 101.4 KB

// per-pixel LDS scratch (dword offsets within a wave's region).
// CORRO aliases TUO: CORRO is live only until FTE1 consumes it; TUO's first
// write is in the K path (after FTE1). 12 waves/block -> 3 waves/SIMD.
#define CMO   0          // cm_h  [8 j][68]: pairs over c
#define TUO   544        // tu_h / u_h [8 h][68]: pairs over c
#define CORRO 544        // corr pairs [44] (aliases TUO)
#define QPO   1088       // generic 64-vec pair buffer [36] (q1 / qn+enc / xn / h1)
#define CCO   1124       // concat pairs [64]
#define PIXDW 1188
#define NWAVES 12
#define LDSDW (WTOT + NWAVES*PIXDW)   // 39600 dw = 158,400 B (<= 160 KB/CU)

// K0: pack all weight matrices to f16-pair layouts in d_ws (runs once, ~2 µs).
__global__ void prep_weights(const float* __restrict__ w1, const float* __restrict__ w2,
                             const float* __restrict__ wq, const float* __restrict__ fw1,
                             const float* __restrict__ fw2, const float* __restrict__ wv,
                             const float* __restrict__ wp, const float* __restrict__ wk,
                             unsigned* __restrict__ ws){
    int idx = blockIdx.x * blockDim.x + threadIdx.x;
    if(idx >= WTOT) return;
    float a = 0.f, b = 0.f;
    if(idx < W2T_OFF){                       // W1T [64][44], src w1 [o=64][c=81]
        int t = idx / 44, cp = idx % 44;
        if(2*cp   < 81) a = w1[t*81 + 2*cp];
        if(2*cp+1 < 81) b = w1[t*81 + 2*cp+1];
    } else if(idx < WQ_OFF){                 // W2T [64][36], src w2 [o=64][c=64]
        int r = idx - W2T_OFF; int t = r / 36, cp = r % 36;
        if(cp < 32){ a = w2[t*64 + 2*cp]; b = w2[t*64 + 2*cp+1]; }
    } else if(idx < FW1_OFF){                // WQ [64][36], src wq [c=64][o=64]
        int r = idx - WQ_OFF; int t = r / 36, cp = r % 36;
        if(cp < 32){ a = wq[(2*cp)*64 + t]; b = wq[(2*cp+1)*64 + t]; }
    } else if(idx < FW2_OFF){                // FW1
        int r = idx - FW1_OFF; int t = r / 36, cp = r % 36;
        if(cp < 32){ a = fw1[(2*cp)*64 + t]; b = fw1[(2*cp+1)*64 + t]; }
    } else if(idx < WV_OFF){                 // FW2
        int r = idx - FW2_OFF; int t = r / 36, cp = r % 36;
        if(cp < 32){ a = fw2[(2*cp)*64 + t]; b = fw2[(2*cp+1)*64 + t]; }
    } else if(idx < WP_OFF){                 // WV [64][68], src wv [c=128][o=64]
        int r = idx - WV_OFF; int t = r / 68, cp = r % 68;
        if(cp < 64){ a = wv[(2*cp)*64 + t]; b = wv[(2*cp+1)*64 + t]; }
    } else if(idx < WK_OFF){                 // WP [64][68], src wp [c=128][o=64]
        int r = idx - WP_OFF; int t = r / 68, cp = r % 68;   // (round-3 bug fixed)
        if(cp < 64){ a = wp[(2*cp)*64 + t]; b = wp[(2*cp+1)*64 + t]; }
    } else {                                 // WK [128][36], src wk [c=128][o=64]
        int r = idx - WK_OFF; int c = r / 36, hp = r % 36;
        if(hp < 32){ a = wk[c*64 + 2*hp]; b = wk[c*64 + 2*hp+1]; }
    }
    ws[idx] = h2u(pk2(a, b));
}

__device__ __forceinline__ float bilin(const float* __restrict__ cmap, float cx, float cy, int e){
    int i = e / 9, j = e - 9*i;
    float sx = cx + (float)(i - 4);
    float sy = cy + (float)(j - 4);
    float x0 = floorf(sx), y0 = floorf(sy);
    float wx = sx - x0,   wy = sy - y0;
    float acc = 0.f;
    #pragma unroll
    for(int dy = 0; dy < 2; dy++){
        #pragma unroll
        for(int dx = 0; dx < 2; dx++){
            float xf = x0 + (float)dx, yf = y0 + (float)dy;
            bool valid = (xf >= 0.f) && (xf <= 63.f) && (yf >= 0.f) && (yf <= 63.f);
            int xi = min(max((int)xf, 0), 63);
            int yi = min(max((int)yf, 0), 63);
            float v = valid ? cmap[yi*64 + xi] : 0.f;
            acc += v * ((dx ? wx : 1.f - wx) * (dy ? wy : 1.f - wy));
        }
    }
    return acc;
}

// Main kernel: grid=256 blocks x 768 threads (12 waves -> 3 waves/SIMD).
// Global wave id gw in [0,3072): gw<2048 -> 3 pixels; gw>=2048 -> 2 pixels +
// one full convex-upsample unit as a registers-only epilogue (load balance).
__global__ __launch_bounds__(768, 1) void decoder_main(
    const float* __restrict__ cost_maps, const float* __restrict__ cost_memory,
    const float* __restrict__ coords1, const float* __restrict__ up_mask,
    const unsigned* __restrict__ ws,
    const float* __restrict__ fte_b1, const float* __restrict__ fte_b2,
    const float* __restrict__ ln1_g, const float* __restrict__ ln1_b,
    const float* __restrict__ ln2_g, const float* __restrict__ ln2_b,
    const float* __restrict__ bq, const float* __restrict__ bv,
    const float* __restrict__ bp, const float* __restrict__ fb1,
    const float* __restrict__ fb2, float* __restrict__ out)
{
    __shared__ unsigned sm[LDSDW];

    const int tid = threadIdx.x;
    const int wv  = tid >> 6;
    const int ln  = tid & 63;
    const int gw  = blockIdx.x * NWAVES + wv;
    const int nPix = (gw < 2048) ? 3 : 2;

    int pix = gw;
    // ---- first-pixel prefetch FIRST: HBM latency hides under the weight copy
    const float4* cm4p = (const float4*)cost_memory;
    float4 cmv0 = cm4p[(size_t)pix*256 +   0 + ln];
    float4 cmv1 = cm4p[(size_t)pix*256 +  64 + ln];
    float4 cmv2 = cm4p[(size_t)pix*256 + 128 + ln];
    float4 cmv3 = cm4p[(size_t)pix*256 + 192 + ln];
    float cx = coords1[(pix >> 12)*8192 + (pix & 4095)];
    float cy = coords1[(pix >> 12)*8192 + 4096 + (pix & 4095)];

    // ---- cooperative weight copy d_ws -> LDS (uint4, coalesced)
    {
        const uint4* src = (const uint4*)ws;
        uint4* dst = (uint4*)sm;
        for(int i = tid; i < WTOT/4; i += 768) dst[i] = src[i];
    }
    // per-lane biases/ln params (lane = feature dim)
    const float b1v = fte_b1[ln], b2v = fte_b2[ln];
    const float g1v = ln1_g[ln], be1 = ln1_b[ln];
    const float g2v = ln2_g[ln], be2 = ln2_b[ln];
    const float bqv = bq[ln], bvv = bv[ln], bpv = bp[ln];
    const float f1v = fb1[ln], f2v = fb2[ln];
    __syncthreads();   // the ONLY block-wide barrier

    float* out_cg = out + 2*2*512*512;
    unsigned* P = sm + WTOT + wv * PIXDW;

    const int h_ = ln & 7;     // head (producer role)
    const int c0 = ln >> 3;    // c sub-lane (producer role)
    const int j_ = ln >> 3;    // token (K-consumer role)
    const int h3 = ln >> 3;    // head of this output dim

    #pragma unroll 1
    for(int g = 0; g < nPix; g++){
        // ---- stage cm pairs into LDS: value l0 = 4*(i4*64+ln), ds_write_b64
        {
            float4 v; int l0, jt, cp0;
            #define STAGE(V, I4) \
                v = V; l0 = 4*((I4)*64 + ln); jt = l0 >> 7; cp0 = (l0 & 127) >> 1; \
                { uint2 pw; pw.x = h2u(pk2(v.x, v.y)); pw.y = h2u(pk2(v.z, v.w)); \
                  *(uint2*)&P[CMO + jt*68 + cp0] = pw; }
            STAGE(cmv0, 0) STAGE(cmv1, 1) STAGE(cmv2, 2) STAGE(cmv3, 3)
            #undef STAGE
        }
        // ---- bilinear correlation window -> corr pairs (both batches issued
        // together: one HBM latency instead of two serial ones)
        {
            const float* cmap = cost_maps + (size_t)pix * 4096;
            float cv = bilin(cmap, cx, cy, ln);
            float c2 = bilin(cmap, cx, cy, 64 + ln);
            float pr = __shfl_xor(cv, 1, 64);
            if((ln & 1) == 0) P[CORRO + (ln >> 1)] = h2u(pk2(cv, pr));
            float pr2 = __shfl_xor(c2, 1, 64);
            if(ln < 17 && (ln & 1) == 0){
                float bb = (ln == 16) ? 0.f : pr2;
                P[CORRO + 32 + (ln >> 1)] = h2u(pk2(c2, bb));
            }
            if(ln < 3) P[CORRO + 41 + ln] = 0u;   // zero pads cp 41..43
        }
        // ---- prefetch next pixel
        int npix = pix + 3072;
        float4 n0, n1, n2, n3; float ncx = 0.f, ncy = 0.f;
        if(g + 1 < nPix){
            n0 = cm4p[(size_t)npix*256 +   0 + ln];
            n1 = cm4p[(size_t)npix*256 +  64 + ln];
            n2 = cm4p[(size_t)npix*256 + 128 + ln];
            n3 = cm4p[(size_t)npix*256 + 192 + ln];
            ncx = coords1[(npix >> 12)*8192 + (npix & 4095)];
            ncy = coords1[(npix >> 12)*8192 + 4096 + (npix & 4095)];
        }
        lds_fence();

        // ---- FTE1: 81->64 + GELU (dual accumulator)
        float q1;
        {
            const uint4* wr = (const uint4*)&sm[W1T_OFF + ln*44];
            const uint4* ar = (const uint4*)&P[CORRO];
            float a0 = b1v, a1 = 0.f;
            #pragma unroll
            for(int gg = 0; gg < 10; gg += 2){
                a0 = dot8(wr[gg],   ar[gg],   a0);
                a1 = dot8(wr[gg+1], ar[gg+1], a1);
            }
            a0 = dot8(wr[10], ar[10], a0);
            q1 = a0 + a1;
        }
        q1 = gelu_exact(q1);
        {   // pack q1 -> QP
            float pr = __shfl_xor(q1, 1, 64);
            if((ln & 1) == 0) P[QPO + (ln >> 1)] = h2u(pk2(q1, pr));
        }
        lds_fence();
        // ---- FTE2: 64->64 (dual accumulator)
        float shortv;
        {
            const uint4* wr = (const uint4*)&sm[W2T_OFF + ln*36];
            const uint4* ar = (const uint4*)&P[QPO];
            float a0 = b2v, a1 = 0.f;
            #pragma unroll
            for(int gg = 0; gg < 8; gg += 2){
                a0 = dot8(wr[gg],   ar[gg],   a0);
                a1 = dot8(wr[gg+1], ar[gg+1], a1);
            }
            shortv = a0 + a1;
        }
        // pack shortv half of the wp-concat NOW (covered by the qn-pack fence)
        {
            float psv = __shfl_xor(shortv, 1, 64);
            if((ln & 1) == 0) P[CCO + 32 + (ln >> 1)] = h2u(pk2(shortv, psv));
        }
        // ---- LN1 + position encoding (fused mean/var butterfly)
        float mean, inv1;
        ln_stats(shortv, mean, inv1);
        float qn = (shortv - mean) * inv1 * g1v + be1;
        {
            int   fi    = ln & 15;
            float coord = (ln < 32) ? cx : cy;
            float ang   = 3.14f * coord * (float)fi / 200.0f;
            float enc   = (ln & 16) ? __cosf(ang) : __sinf(ang);
            float qv    = qn + enc;
            float pr = __shfl_xor(qv, 1, 64);
            if((ln & 1) == 0) P[QPO + (ln >> 1)] = h2u(pk2(qv, pr));
        }
        lds_fence();
        // ---- Wq (dual accumulator); qlin stays in registers — the K path
        // gathers its 8 per-head values by shuffle (no LDS round-trip/fence).
        float qlin;
        {
            const uint4* wr = (const uint4*)&sm[WQ_OFF + ln*36];
            const uint4* ar = (const uint4*)&P[QPO];
            float a0 = bqv, a1 = 0.f;
            #pragma unroll
            for(int gg = 0; gg < 8; gg += 2){
                a0 = dot8(wr[gg],   ar[gg],   a0);
                a1 = dot8(wr[gg+1], ar[gg+1], a1);
            }
            qlin = a0 + a1;
        }
        // ---- K path: t[c,h] = sum_d qlin[h*8+d] wk[c,h*8+d]  (bk cancels)
        {
            uint4 qh4;
            {
                float v0 = __shfl(qlin, h_*8 + 0, 64), v1 = __shfl(qlin, h_*8 + 1, 64);
                float v2 = __shfl(qlin, h_*8 + 2, 64), v3 = __shfl(qlin, h_*8 + 3, 64);
                float v4 = __shfl(qlin, h_*8 + 4, 64), v5 = __shfl(qlin, h_*8 + 5, 64);
                float v6 = __shfl(qlin, h_*8 + 6, 64), v7 = __shfl(qlin, h_*8 + 7, 64);
                qh4.x = h2u(pk2(v0, v1)); qh4.y = h2u(pk2(v2, v3));
                qh4.z = h2u(pk2(v4, v5)); qh4.w = h2u(pk2(v6, v7));
            }
            #pragma unroll
            for(int i = 0; i < 16; i++){
                int c = c0 + 8*i;
                uint4 wk4 = *(const uint4*)&sm[WK_OFF + c*36 + h_*4];
                float tv = dot8(wk4, qh4, 0.f);
                float prt = __shfl_xor(tv, 8, 64);
                if((c0 & 1) == 0) P[TUO + h_*68 + (c0 >> 1) + 4*i] = h2u(pk2(tv, prt));
            }
        }
        lds_fence();
        // s[j,h] = sum_cp dot2(cm[j], t[h])  (quad accumulator)
        float sacc;
        {
            const int hk = ln & 7;
            const uint4* cmr = (const uint4*)&P[CMO + j_*68];
            const uint4* tur = (const uint4*)&P[TUO + hk*68];
            float s0 = 0.f, s1 = 0.f, s2 = 0.f, s3 = 0.f;
            #pragma unroll
            for(int gg = 0; gg < 16; gg += 4){
                s0 = dot8(cmr[gg],   tur[gg],   s0);
                s1 = dot8(cmr[gg+1], tur[gg+1], s1);
                s2 = dot8(cmr[gg+2], tur[gg+2], s2);
                s3 = dot8(cmr[gg+3], tur[gg+3], s3);
            }
            sacc = (s0 + s1) + (s2 + s3);
        }
        // softmax over tokens (lanes ln = j*8+h; reduce over j); probs stay in regs
        float p;
        {
            float sc = sacc * 0.35355339059327373f;
            float mx = sc;
            mx = fmaxf(mx, __shfl_xor(mx,  8, 64));
            mx = fmaxf(mx, __shfl_xor(mx, 16, 64));
            mx = fmaxf(mx, __shfl_xor(mx, 32, 64));
            float ex = __expf(sc - mx);
            float se = ex;
            se += __shfl_xor(se,  8, 64);
            se += __shfl_xor(se, 16, 64);
            se += __shfl_xor(se, 32, 64);
            p = ex * fast_rcp(se);
        }
        // ---- V path: u[h][cp] = sum_j a[j,h] cm[j][cp]; contiguous b128 blocks
        {
            float av[8];
            #pragma unroll
            for(int j = 0; j < 8; j++) av[j] = __shfl(p, j*8 + h_, 64);
            h2 u0 = pk2(0.f,0.f), u1 = u0, u2 = u0, u3 = u0;
            h2 u4 = u0, u5 = u0, u6 = u0, u7 = u0;
            #pragma unroll
            for(int j = 0; j < 8; j++){
                h2 aj = pk2(av[j], av[j]);
                const uint4* cmr = (const uint4*)&P[CMO + j*68 + 8*c0];
                uint4 qa = cmr[0], qb = cmr[1];
                u0 += aj * uh2(qa.x); u1 += aj * uh2(qa.y);
                u2 += aj * uh2(qa.z); u3 += aj * uh2(qa.w);
                u4 += aj * uh2(qb.x); u5 += aj * uh2(qb.y);
                u6 += aj * uh2(qb.z); u7 += aj * uh2(qb.w);
            }
            uint4 wa; wa.x = h2u(u0); wa.y = h2u(u1); wa.z = h2u(u2); wa.w = h2u(u3);
            uint4 wb; wb.x = h2u(u4); wb.y = h2u(u5); wb.z = h2u(u6); wb.w = h2u(u7);
            *(uint4*)&P[TUO + h_*68 + 8*c0]     = wa;
            *(uint4*)&P[TUO + h_*68 + 8*c0 + 4] = wb;
        }
        lds_fence();
        // attno = bv + sum_c u[h3][c] wv[c][ln]  (quad accumulator)
        float attno;
        {
            const uint4* ur = (const uint4*)&P[TUO + h3*68];
            const uint4* wr = (const uint4*)&sm[WV_OFF + ln*68];
            float a0 = bvv, a1 = 0.f, a2 = 0.f, a3 = 0.f;
            #pragma unroll
            for(int gg = 0; gg < 16; gg += 4){
                a0 = dot8(ur[gg],   wr[gg],   a0);
                a1 = dot8(ur[gg+1], wr[gg+1], a1);
                a2 = dot8(ur[gg+2], wr[gg+2], a2);
                a3 = dot8(ur[gg+3], wr[gg+3], a3);
            }
            attno = (a0 + a1) + (a2 + a3);
        }
        // ---- wp on concat(attno, short) + residual
        {
            float pa = __shfl_xor(attno, 1, 64);
            if((ln & 1) == 0) P[CCO + (ln >> 1)] = h2u(pk2(attno, pa));
        }
        lds_fence();
        float x;
        {
            const uint4* wr = (const uint4*)&sm[WP_OFF + ln*68];
            const uint4* ar = (const uint4*)&P[CCO];
            float a0 = bpv, a1 = 0.f, a2 = 0.f, a3 = 0.f;
            #pragma unroll
            for(int gg = 0; gg < 16; gg += 4){
                a0 = dot8(wr[gg],   ar[gg],   a0);
                a1 = dot8(wr[gg+1], ar[gg+1], a1);
                a2 = dot8(wr[gg+2], ar[gg+2], a2);
                a3 = dot8(wr[gg+3], ar[gg+3], a3);
            }
            x = (a0 + a1) + (a2 + a3);
        }
        x += shortv;
        // ---- LN2 + FFN + residual
        float m2, inv2;
        ln_stats(x, m2, inv2);
        float xn = (x - m2) * inv2 * g2v + be2;
        {
            float pr = __shfl_xor(xn, 1, 64);
            if((ln & 1) == 0) P[QPO + (ln >> 1)] = h2u(pk2(xn, pr));
        }
        lds_fence();
        float h1v;
        {
            const uint4* wr = (const uint4*)&sm[FW1_OFF + ln*36];
            const uint4* ar = (const uint4*)&P[QPO];
            float a0 = f1v, a1 = 0.f;
            #pragma unroll
            for(int gg = 0; gg < 8; gg += 2){
                a0 = dot8(wr[gg],   ar[gg],   a0);
                a1 = dot8(wr[gg+1], ar[gg+1], a1);
            }
            h1v = a0 + a1;
        }
        h1v = gelu_exact(h1v);
        {
            float pr = __shfl_xor(h1v, 1, 64);
            if((ln & 1) == 0) P[QPO + (ln >> 1)] = h2u(pk2(h1v, pr));
        }
        lds_fence();
        float f2;
        {
            const uint4* wr = (const uint4*)&sm[FW2_OFF + ln*36];
            const uint4* ar = (const uint4*)&P[QPO];
            float a0 = f2v, a1 = 0.f;
            #pragma unroll
            for(int gg = 0; gg < 8; gg += 2){
                a0 = dot8(wr[gg],   ar[gg],   a0);
                a1 = dot8(wr[gg+1], ar[gg+1], a1);
            }
            f2 = a0 + a1;
        }
        x += f2;
        // store: cost_global [B,64,64,64]
        {
            int bb = pix >> 12, hh = (pix >> 6) & 63, ww = pix & 63;
            out_cg[(((size_t)(bb*64 + ln))*64 + hh)*64 + ww] = x;
        }
        pix = npix; cx = ncx; cy = ncy;
        cmv0 = n0; cmv1 = n1; cmv2 = n2; cmv3 = n3;
    }

    // ---- epilogue: convex upsampling. The 2-pixel waves (gw >= 2048) each do
    // one FULL (b,h,r) unit — registers + shuffles only, no LDS, no barrier.
    if(gw >= 2048){
        const int u  = gw - 2048;                    // unit in [0,1024)
        const int ub = u >> 9, uh = (u >> 3) & 63, ur = u & 7;
        const int w  = ln;

        float fx[3], fy[3];
        #pragma unroll
        for(int i = 0; i < 3; i++){
            int hh = uh + i - 1;
            bool ok = (hh >= 0) && (hh < 64);
            int hc = min(max(hh, 0), 63);
            float cxv = coords1[((ub*2 + 0)*64 + hc)*64 + w];
            float cyv = coords1[((ub*2 + 1)*64 + hc)*64 + w];
            fx[i] = ok ? 8.f * (cxv - (float)w)  : 0.f;
            fy[i] = ok ? 8.f * (cyv - (float)hh) : 0.f;
        }
        float fxm[3], fxp[3], fym[3], fyp[3];
        #pragma unroll
        for(int i = 0; i < 3; i++){
            fxm[i] = __shfl(fx[i], w - 1, 64);
            fxp[i] = __shfl(fx[i], w + 1, 64);
            fym[i] = __shfl(fy[i], w - 1, 64);
            fyp[i] = __shfl(fy[i], w + 1, 64);
            if(w == 0) { fxm[i] = 0.f; fym[i] = 0.f; }
            if(w == 63){ fxp[i] = 0.f; fyp[i] = 0.f; }
        }
        #pragma unroll
        for(int sh = 0; sh < 8; sh += 4){
            float m[36];
            #pragma unroll
            for(int k = 0; k < 9; k++){
                #pragma unroll
                for(int si = 0; si < 4; si++){
                    int c = k*64 + ur*8 + sh + si;
                    m[k*4 + si] = up_mask[(((size_t)ub*576 + c)*64 + uh)*64 + w];
                }
            }
            float outx[4], outy[4];
            #pragma unroll
            for(int si = 0; si < 4; si++){
                float mx = m[si];
                #pragma unroll
                for(int k = 1; k < 9; k++) mx = fmaxf(mx, m[k*4 + si]);
                float e, se = 0.f, ox = 0.f, oy = 0.f;
                #pragma unroll
                for(int k = 0; k < 9; k++){
                    e = __expf(m[k*4 + si] - mx);
                    se += e;
                    int i = k / 3, j = k % 3;
                    float fxv = (j == 0) ? fxm[i] : ((j == 1) ? fx[i] : fxp[i]);
                    float fyv = (j == 0) ? fym[i] : ((j == 1) ? fy[i] : fyp[i]);
                    ox += e * fxv;
                    oy += e * fyv;
                }
                float inv = fast_rcp(se);
                outx[si] = ox * inv;
                outy[si] = oy * inv;
            }
            size_t row = (size_t)(uh*8 + ur) * 512 + w*8 + sh;
            *(float4*)&out[(size_t)(ub*2 + 0)*262144 + row] = *(const float4*)outx;
            *(float4*)&out[(size_t)(ub*2 + 1)*262144 + row] = *(const float4*)outy;
        }
    }
}

extern "C" void kernel_launch(void* const* d_in, const int* in_sizes, int n_in,
                              void* d_out, int out_size, void* d_ws, size_t ws_size,
                              hipStream_t stream)
{
    const float* cost_maps   = (const float*)d_in[0];
    const float* cost_memory = (const float*)d_in[1];
    const float* coords1     = (const float*)d_in[2];
    const float* up_mask     = (const float*)d_in[3];
    const float* fte_w1      = (const float*)d_in[4];
    const float* fte_b1      = (const float*)d_in[5];
    const float* fte_w2      = (const float*)d_in[6];
    const float* fte_b2      = (const float*)d_in[7];
    const float* ln1_g       = (const float*)d_in[8];
    const float* ln1_b       = (const float*)d_in[9];
    const float* ln2_g       = (const float*)d_in[10];
    const float* ln2_b       = (const float*)d_in[11];
    const float* wq          = (const float*)d_in[12];
    const float* bq          = (const float*)d_in[13];
    const float* wk          = (const float*)d_in[14];
    const float* bv          = (const float*)d_in[17];
    const float* wv          = (const float*)d_in[16];
    const float* wp          = (const float*)d_in[18];
    const float* bp          = (const float*)d_in[19];
    const float* fw1         = (const float*)d_in[20];
    const float* fb1         = (const float*)d_in[21];
    const float* fw2         = (const float*)d_in[22];
    const float* fb2         = (const float*)d_in[23];
    float* out = (float*)d_out;
    unsigned* wsu = (unsigned*)d_ws;

    prep_weights<<<(WTOT + 511)/512, 512, 0, stream>>>(
        fte_w1, fte_w2, wq, fw1, fw2, wv, wp, wk, wsu);

    decoder_main<<<256, 768, 0, stream>>>(
        cost_maps, cost_memory, coords1, up_mask, wsu,
        fte_b1, fte_b2, ln1_g, ln1_b, ln2_g, ln2_b,
        bq, bv, bp, fb1, fb2,
        out);
}